// Round 1
// baseline (27406.006 us; speedup 1.0000x reference)
//
#include <hip/hip_runtime.h>
#include <stdint.h>

#define T_LEN 1024
#define B_SZ  64
#define I_SZ  256
#define H_SZ  512
#define O_SZ  128
#define WP    776   // padded K pitch (768 + 8) in ushorts

// workspace layout (bytes)
#define L1_OFF  0ull                  // 1024 steps * 4 groups * 128B
#define L2_OFF  524288ull             // 1024 steps * 128B
#define HB_OFF  655360ull             // 2 bufs * 2 dir * 64 * 512 * 2B = 262144
#define Y_OFF   917504ull             // 64*1024*1024*2 = 134217728
#define XBF_OFF 135135232ull          // 64*1024*256*2  = 33554432
#define MEMSET_BYTES 917504ull        // counters + h buffers

typedef __attribute__((ext_vector_type(8))) short short8;
typedef __attribute__((ext_vector_type(4))) float f32x4;

__device__ __forceinline__ unsigned short f2bf(float f) {
  unsigned u = __float_as_uint(f);
  u += 0x7fffu + ((u >> 16) & 1u);
  return (unsigned short)(u >> 16);
}
__device__ __forceinline__ ushort4 cvt4(float4 v) {
  ushort4 p;
  p.x = f2bf(v.x); p.y = f2bf(v.y); p.z = f2bf(v.z); p.w = f2bf(v.w);
  return p;
}
__device__ __forceinline__ float sigm(float x) { return 1.0f / (1.0f + __expf(-x)); }
__device__ __forceinline__ float tanh_f(float x) { return 1.0f - 2.0f / (1.0f + __expf(2.0f * x)); }

// ---------------- input fp32 -> bf16 conversion ----------------
__global__ void __launch_bounds__(256) cvt_x(const float* __restrict__ x,
                                             unsigned short* __restrict__ xb) {
  size_t i = ((size_t)blockIdx.x * 256 + threadIdx.x) * 8;
  float4 a = *(const float4*)(x + i);
  float4 b = *(const float4*)(x + i + 4);
  *(ushort4*)(xb + i)     = cvt4(a);
  *(ushort4*)(xb + i + 4) = cvt4(b);
}

// ---------------- persistent bidirectional LSTM scan ----------------
// grid 128 (= 64 WGs/dir: 2 batch-groups x 32 unit-groups), 512 threads.
// Weights live in registers as MFMA B-fragments; h ping-pongs through global.
__global__ void __launch_bounds__(512, 2)
lstm_scan(const unsigned short* __restrict__ xbf,
          const float* __restrict__ WihF, const float* __restrict__ WhhF,
          const float* __restrict__ bihF, const float* __restrict__ bhhF,
          const float* __restrict__ WihB, const float* __restrict__ WhhB,
          const float* __restrict__ bihB, const float* __restrict__ bhhB,
          unsigned char* __restrict__ ws, float* __restrict__ out)
{
  __shared__ unsigned short xh[32 * WP];   // [m=32 batch][k=768: x_t | h_prev]
  __shared__ float gbuf[4][32][16];        // [gate][batch][unit]
  __shared__ float cst[32][16];            // cell state, fp32, WG-private

  const int tid  = threadIdx.x;
  const int wave = tid >> 6;
  const int lane = tid & 63;
  const int nl   = lane & 15;
  const int q16  = lane >> 4;

  const int wg  = blockIdx.x;
  const int d   = wg >> 6;        // 0 fwd, 1 bwd
  const int loc = wg & 63;
  const int b0  = (loc >> 5) * 32;   // batch-group
  const int u0  = (loc & 31) * 16;   // unit-group
  const int grp = wg >> 5;           // barrier L1 group (0..3)

  const float* Wih = d ? WihB : WihF;
  const float* Whh = d ? WhhB : WhhF;
  const float* bih = d ? bihB : bihF;
  const float* bhh = d ? bhhB : bhhF;

  const int gate = wave >> 1;   // 0=i 1=f 2=g 3=o
  const int mt   = wave & 1;    // batch half-tile

  // ---- preload this wave's B fragments (its gate's 16 rows, K=768) ----
  short8 wfrag[24];
  {
    const int row = gate * H_SZ + u0 + nl;
    const float* wi = Wih + (size_t)row * I_SZ;
    const float* wh = Whh + (size_t)row * H_SZ;
#pragma unroll
    for (int kk = 0; kk < 24; ++kk) {
      const float* src = (kk < 8) ? (wi + kk * 32 + q16 * 8)
                                  : (wh + (kk - 8) * 32 + q16 * 8);
      float4 v0 = ((const float4*)src)[0];
      float4 v1 = ((const float4*)src)[1];
      short8 w;
      w[0] = (short)f2bf(v0.x); w[1] = (short)f2bf(v0.y);
      w[2] = (short)f2bf(v0.z); w[3] = (short)f2bf(v0.w);
      w[4] = (short)f2bf(v1.x); w[5] = (short)f2bf(v1.y);
      w[6] = (short)f2bf(v1.z); w[7] = (short)f2bf(v1.w);
      wfrag[kk] = w;
    }
  }
  const float bias = bih[gate * H_SZ + u0 + nl] + bhh[gate * H_SZ + u0 + nl];

  cst[tid >> 4][tid & 15] = 0.0f;

  unsigned* l1base = (unsigned*)(ws + L1_OFF);
  unsigned* l2base = (unsigned*)(ws + L2_OFF);
  unsigned short* hbuf = (unsigned short*)(ws + HB_OFF);
  unsigned short* ybuf = (unsigned short*)(ws + Y_OFF);

  for (int s = 0; s < T_LEN; ++s) {
    const int t  = d ? (T_LEN - 1 - s) : s;
    const int rb = (s & 1) ^ 1, wb = s & 1;

    // ---- stage x_t (bf16) ----
    {
      int m = tid >> 4, seg = tid & 15;
      const uint4* src = (const uint4*)(xbf + ((size_t)(b0 + m) * T_LEN + t) * I_SZ + seg * 16);
      uint4* dst = (uint4*)(xh + m * WP + seg * 16);
      dst[0] = src[0]; dst[1] = src[1];
    }
    // ---- stage h_{t-1} (bf16, full H) ----
    {
      int m = tid >> 4, seg = tid & 15;
      const uint4* src = (const uint4*)(hbuf + ((size_t)((rb * 2 + d) * B_SZ + b0 + m)) * H_SZ + seg * 32);
      uint4* dst = (uint4*)(xh + m * WP + 256 + seg * 32);
      dst[0] = src[0]; dst[1] = src[1]; dst[2] = src[2]; dst[3] = src[3];
    }
    __syncthreads();

    // ---- gates = [x|h] @ Wcat^T  (one 16x16 tile per wave, K=768) ----
    f32x4 acc = {0.f, 0.f, 0.f, 0.f};
    const unsigned short* ar = xh + (mt * 16 + nl) * WP + q16 * 8;
#pragma unroll
    for (int kk = 0; kk < 24; ++kk) {
      short8 a = *(const short8*)(ar + kk * 32);
      acc = __builtin_amdgcn_mfma_f32_16x16x32_bf16(a, wfrag[kk], acc, 0, 0, 0);
    }

    // ---- bias + activation -> gbuf ----
#pragma unroll
    for (int r = 0; r < 4; ++r) {
      float v = acc[r] + bias;
      v = (gate == 2) ? tanh_f(v) : sigm(v);
      gbuf[gate][mt * 16 + q16 * 4 + r][nl] = v;
    }
    __syncthreads();

    // ---- cell/hidden update: 512 threads <-> 32 batch x 16 units ----
    {
      int m = tid >> 4, n = tid & 15;
      float gi = gbuf[0][m][n], gf = gbuf[1][m][n];
      float gg = gbuf[2][m][n], go = gbuf[3][m][n];
      float c = gf * cst[m][n] + gi * gg;
      cst[m][n] = c;
      float h = go * tanh_f(c);
      unsigned short hv = f2bf(h);
      hbuf[((size_t)((wb * 2 + d) * B_SZ + b0 + m)) * H_SZ + u0 + n] = hv;
      ybuf[((size_t)(b0 + m) * T_LEN + t) * (2 * H_SZ) + d * H_SZ + u0 + n] = hv;
      if (s == T_LEN - 1) {
        size_t hi = (size_t)(d * B_SZ + b0 + m) * H_SZ + u0 + n;
        out[8388608ull + hi] = h;            // h_n
        out[8388608ull + 65536ull + hi] = c; // c_n
      }
    }

    // ---- grid barrier (release h_t, acquire before next read) ----
    if (s < T_LEN - 1) {
      __builtin_amdgcn_fence(__ATOMIC_RELEASE, "agent");
      __syncthreads();
      if (tid == 0) {
        unsigned* l1 = l1base + ((size_t)s * 4 + grp) * 32;
        unsigned* l2 = l2base + (size_t)s * 32;
        if (atomicAdd(l1, 1u) == 31u) atomicAdd(l2, 1u);
        while (__hip_atomic_load(l2, __ATOMIC_RELAXED, __HIP_MEMORY_SCOPE_AGENT) < 4u)
          __builtin_amdgcn_s_sleep(2);
      }
      __syncthreads();
      __builtin_amdgcn_fence(__ATOMIC_ACQUIRE, "agent");
    }
  }
}

// ---------------- output projection: out = y @ W_out^T + b_out ----------------
// 512 blocks, each: 128 bt-rows x 128 outs, K=1024 in 4 chunks of 256.
__global__ void __launch_bounds__(256, 1)
proj(const unsigned short* __restrict__ y, const float* __restrict__ Wout,
     const float* __restrict__ bout, float* __restrict__ out)
{
  __shared__ unsigned short ys[128 * 264];
  __shared__ unsigned short wst[128 * 264];

  const int tid  = threadIdx.x;
  const int wave = tid >> 6;
  const int lane = tid & 63;
  const int nl   = lane & 15;
  const int q16  = lane >> 4;
  const int m0   = blockIdx.x * 128;

  f32x4 acc[2][8];
#pragma unroll
  for (int a = 0; a < 2; ++a)
#pragma unroll
    for (int b = 0; b < 8; ++b) acc[a][b] = (f32x4){0.f, 0.f, 0.f, 0.f};

  for (int k0 = 0; k0 < 1024; k0 += 256) {
    // stage y chunk [128 rows][256] bf16
    {
      int r = tid >> 1, half = tid & 1;
      const uint4* src = (const uint4*)(y + (size_t)(m0 + r) * 1024 + k0 + half * 128);
      uint4* dst = (uint4*)(ys + r * 264 + half * 128);
#pragma unroll
      for (int q = 0; q < 16; ++q) dst[q] = src[q];
    }
    // stage W chunk [128 outs][256] fp32 -> bf16
    {
      int r = tid >> 1, half = tid & 1;
      const float4* src = (const float4*)(Wout + (size_t)r * 1024 + k0 + half * 128);
      unsigned short* wd = wst + r * 264 + half * 128;
#pragma unroll
      for (int q = 0; q < 32; ++q) *(ushort4*)(wd + q * 4) = cvt4(src[q]);
    }
    __syncthreads();

#pragma unroll
    for (int kk = 0; kk < 8; ++kk) {
      const int ko = kk * 32 + q16 * 8;
      short8 bfr[8];
#pragma unroll
      for (int nt = 0; nt < 8; ++nt)
        bfr[nt] = *(const short8*)(wst + (nt * 16 + nl) * 264 + ko);
#pragma unroll
      for (int mtt = 0; mtt < 2; ++mtt) {
        short8 a = *(const short8*)(ys + ((wave * 2 + mtt) * 16 + nl) * 264 + ko);
#pragma unroll
        for (int nt = 0; nt < 8; ++nt)
          acc[mtt][nt] = __builtin_amdgcn_mfma_f32_16x16x32_bf16(a, bfr[nt], acc[mtt][nt], 0, 0, 0);
      }
    }
    __syncthreads();
  }

  // epilogue
#pragma unroll
  for (int mtt = 0; mtt < 2; ++mtt) {
#pragma unroll
    for (int nt = 0; nt < 8; ++nt) {
      int col = nt * 16 + nl;
      float bo = bout[col];
      int rowb = m0 + (wave * 2 + mtt) * 16 + q16 * 4;
#pragma unroll
      for (int r = 0; r < 4; ++r)
        out[(size_t)(rowb + r) * O_SZ + col] = acc[mtt][nt][r] + bo;
    }
  }
}

extern "C" void kernel_launch(void* const* d_in, const int* in_sizes, int n_in,
                              void* d_out, int out_size, void* d_ws, size_t ws_size,
                              hipStream_t stream) {
  const float* x    = (const float*)d_in[0];
  const float* WihF = (const float*)d_in[1];
  const float* WhhF = (const float*)d_in[2];
  const float* bihF = (const float*)d_in[3];
  const float* bhhF = (const float*)d_in[4];
  const float* WihB = (const float*)d_in[5];
  const float* WhhB = (const float*)d_in[6];
  const float* bihB = (const float*)d_in[7];
  const float* bhhB = (const float*)d_in[8];
  const float* Wout = (const float*)d_in[9];
  const float* bout = (const float*)d_in[10];
  float* out = (float*)d_out;
  unsigned char* ws = (unsigned char*)d_ws;

  hipMemsetAsync(ws, 0, (size_t)MEMSET_BYTES, stream);
  cvt_x<<<8192, 256, 0, stream>>>(x, (unsigned short*)(ws + XBF_OFF));
  lstm_scan<<<128, 512, 0, stream>>>((const unsigned short*)(ws + XBF_OFF),
                                     WihF, WhhF, bihF, bhhF,
                                     WihB, WhhB, bihB, bhhB,
                                     ws, out);
  proj<<<512, 256, 0, stream>>>((const unsigned short*)(ws + Y_OFF), Wout, bout, out);
}

// Round 2
// 3710.667 us; speedup vs baseline: 7.3857x; 7.3857x over previous
//
#include <hip/hip_runtime.h>
#include <stdint.h>

#define T_LEN 1024
#define B_SZ  64
#define I_SZ  256
#define H_SZ  512
#define O_SZ  128
#define WP    776   // padded K pitch (768 + 8) in ushorts

// workspace layout (bytes)
#define L1_OFF  0ull                  // 1024 steps * 4 chains * 128B = 524288
#define HB_OFF  524288ull             // 2 bufs * 2 dir * 64 * 512 * 2B = 262144
#define Y_OFF   786432ull             // 64*1024*1024*2 = 134217728
#define XBF_OFF 135004160ull          // 64*1024*256*2  = 33554432
#define MEMSET_BYTES 786432ull        // counters + h buffers

typedef __attribute__((ext_vector_type(8))) short short8;
typedef __attribute__((ext_vector_type(4))) float f32x4;

__device__ __forceinline__ unsigned short f2bf(float f) {
  unsigned u = __float_as_uint(f);
  u += 0x7fffu + ((u >> 16) & 1u);
  return (unsigned short)(u >> 16);
}
__device__ __forceinline__ ushort4 cvt4(float4 v) {
  ushort4 p;
  p.x = f2bf(v.x); p.y = f2bf(v.y); p.z = f2bf(v.z); p.w = f2bf(v.w);
  return p;
}
__device__ __forceinline__ float sigm(float x) { return 1.0f / (1.0f + __expf(-x)); }
__device__ __forceinline__ float tanh_f(float x) { return 1.0f - 2.0f / (1.0f + __expf(2.0f * x)); }

// ---------------- input fp32 -> bf16 conversion ----------------
__global__ void __launch_bounds__(256) cvt_x(const float* __restrict__ x,
                                             unsigned short* __restrict__ xb) {
  size_t i = ((size_t)blockIdx.x * 256 + threadIdx.x) * 8;
  float4 a = *(const float4*)(x + i);
  float4 b = *(const float4*)(x + i + 4);
  *(ushort4*)(xb + i)     = cvt4(a);
  *(ushort4*)(xb + i + 4) = cvt4(b);
}

// ---------------- persistent bidirectional LSTM scan ----------------
// grid 128 = 4 independent chains (dir x batch-group) x 32 unit-group WGs.
// Weights live in registers as MFMA B-fragments. h exchanged through MALL
// via per-access agent-scope (sc1) loads/stores — NO cache-wide fences.
__global__ void __launch_bounds__(512, 2)
lstm_scan(const unsigned short* __restrict__ xbf,
          const float* __restrict__ WihF, const float* __restrict__ WhhF,
          const float* __restrict__ bihF, const float* __restrict__ bhhF,
          const float* __restrict__ WihB, const float* __restrict__ WhhB,
          const float* __restrict__ bihB, const float* __restrict__ bhhB,
          unsigned char* __restrict__ ws, float* __restrict__ out)
{
  __shared__ unsigned short xh[32 * WP];   // [m=32 batch][k=768: x_t | h_prev]
  __shared__ float gbuf[4][32][18];        // [gate][batch][unit] (pitch 18: no 4-way)
  __shared__ float cst[32][18];            // cell state, fp32, WG-private

  const int tid  = threadIdx.x;
  const int wave = tid >> 6;
  const int lane = tid & 63;
  const int nl   = lane & 15;
  const int q16  = lane >> 4;

  const int wg  = blockIdx.x;
  const int d   = wg >> 6;           // 0 fwd, 1 bwd
  const int loc = wg & 63;
  const int b0  = (loc >> 5) * 32;   // batch-group
  const int u0  = (loc & 31) * 16;   // unit-group
  const int grp = wg >> 5;           // chain id (0..3)

  const float* Wih = d ? WihB : WihF;
  const float* Whh = d ? WhhB : WhhF;
  const float* bih = d ? bihB : bihF;
  const float* bhh = d ? bhhB : bhhF;

  const int gate = wave >> 1;   // 0=i 1=f 2=g 3=o
  const int mt   = wave & 1;    // batch half-tile

  // ---- preload this wave's B fragments (its gate's 16 rows, K=768) ----
  short8 wfrag[24];
  {
    const int row = gate * H_SZ + u0 + nl;
    const float* wi = Wih + (size_t)row * I_SZ;
    const float* wh = Whh + (size_t)row * H_SZ;
#pragma unroll
    for (int kk = 0; kk < 24; ++kk) {
      const float* src = (kk < 8) ? (wi + kk * 32 + q16 * 8)
                                  : (wh + (kk - 8) * 32 + q16 * 8);
      float4 v0 = ((const float4*)src)[0];
      float4 v1 = ((const float4*)src)[1];
      short8 w;
      w[0] = (short)f2bf(v0.x); w[1] = (short)f2bf(v0.y);
      w[2] = (short)f2bf(v0.z); w[3] = (short)f2bf(v0.w);
      w[4] = (short)f2bf(v1.x); w[5] = (short)f2bf(v1.y);
      w[6] = (short)f2bf(v1.z); w[7] = (short)f2bf(v1.w);
      wfrag[kk] = w;
    }
  }
  const float bias = bih[gate * H_SZ + u0 + nl] + bhh[gate * H_SZ + u0 + nl];

  cst[tid >> 4][tid & 15] = 0.0f;

  unsigned* cntbase = (unsigned*)(ws + L1_OFF);
  unsigned* hbuf32  = (unsigned*)(ws + HB_OFF);
  unsigned* ybuf32  = (unsigned*)(ws + Y_OFF);
  unsigned* xh32    = (unsigned*)xh;

  const int sm = tid >> 4, sseg = tid & 15;   // x-staging coords

  // prime x prefetch for s=0
  int t_next = d ? (T_LEN - 1) : 0;
  uint4 px0, px1;
  {
    const uint4* src = (const uint4*)(xbf + ((size_t)(b0 + sm) * T_LEN + t_next) * I_SZ + sseg * 16);
    px0 = src[0]; px1 = src[1];
  }

  for (int s = 0; s < T_LEN; ++s) {
    const int t  = t_next;
    const int rb = (s & 1) ^ 1, wb = s & 1;

    // ---- write prefetched x_t to LDS ----
    {
      uint4* dst = (uint4*)(xh + sm * WP + sseg * 16);
      dst[0] = px0; dst[1] = px1;
    }
    // ---- stage h_{t-1}: agent-scope (sc1) loads from MALL -> LDS ----
    {
      unsigned hv[16];
#pragma unroll
      for (int j = 0; j < 16; ++j) {
        int lin = j * 512 + tid;                  // 8192 uints = 32 x H bf16
        hv[j] = __hip_atomic_load(hbuf32 + ((size_t)((rb * 2 + d) * B_SZ + b0) * 256 + lin),
                                  __ATOMIC_RELAXED, __HIP_MEMORY_SCOPE_AGENT);
      }
#pragma unroll
      for (int j = 0; j < 16; ++j) {
        int lin = j * 512 + tid;
        int m = lin >> 8, col = lin & 255;
        xh32[m * (WP / 2) + 128 + col] = hv[j];
      }
    }
    __syncthreads();

    // ---- gates = [x|h] @ Wcat^T  (one 16x16 tile per wave, K=768) ----
    f32x4 acc = {0.f, 0.f, 0.f, 0.f};
    const unsigned short* ar = xh + (mt * 16 + nl) * WP + q16 * 8;
#pragma unroll
    for (int kk = 0; kk < 24; ++kk) {
      short8 a = *(const short8*)(ar + kk * 32);
      acc = __builtin_amdgcn_mfma_f32_16x16x32_bf16(a, wfrag[kk], acc, 0, 0, 0);
    }

    // ---- bias + activation -> gbuf ----
#pragma unroll
    for (int r = 0; r < 4; ++r) {
      float v = acc[r] + bias;
      v = (gate == 2) ? tanh_f(v) : sigm(v);
      gbuf[gate][mt * 16 + q16 * 4 + r][nl] = v;
    }
    __syncthreads();

    // ---- cell/hidden update ----
    {
      int m = tid >> 4, n = tid & 15;
      float gi = gbuf[0][m][n], gf = gbuf[1][m][n];
      float gg = gbuf[2][m][n], go = gbuf[3][m][n];
      float c = gf * cst[m][n] + gi * gg;
      cst[m][n] = c;
      float h = go * tanh_f(c);
      unsigned hbits = f2bf(h);
      unsigned other = __shfl_xor(hbits, 1);
      if ((tid & 1) == 0) {
        unsigned packed = hbits | (other << 16);
        size_t hi = (size_t)((wb * 2 + d) * B_SZ + b0 + m) * 256 + (u0 + n) / 2;
        __hip_atomic_store(hbuf32 + hi, packed, __ATOMIC_RELAXED, __HIP_MEMORY_SCOPE_AGENT);
        size_t yi = ((size_t)(b0 + m) * T_LEN + t) * 512 + (d * H_SZ + u0 + n) / 2;
        ybuf32[yi] = packed;                      // plain cached store (read next kernel)
      }
      if (s == T_LEN - 1) {
        size_t hi = (size_t)(d * B_SZ + b0 + m) * H_SZ + u0 + n;
        out[8388608ull + hi] = h;            // h_n
        out[8388608ull + 65536ull + hi] = c; // c_n
      }
    }

    if (s < T_LEN - 1) {
      // ---- prefetch next x (independent of barrier) ----
      t_next = d ? (T_LEN - 2 - s) : (s + 1);
      {
        const uint4* src = (const uint4*)(xbf + ((size_t)(b0 + sm) * T_LEN + t_next) * I_SZ + sseg * 16);
        px0 = src[0]; px1 = src[1];
      }
      // ---- chain-local barrier: drain stores, then 32-arrival counter ----
      __builtin_amdgcn_s_waitcnt(0);            // h sc1 stores complete at MALL
      __syncthreads();
      if (tid == 0) {
        unsigned* cnt = cntbase + ((size_t)s * 4 + grp) * 32;
        __hip_atomic_fetch_add(cnt, 1u, __ATOMIC_RELAXED, __HIP_MEMORY_SCOPE_AGENT);
        while (__hip_atomic_load(cnt, __ATOMIC_RELAXED, __HIP_MEMORY_SCOPE_AGENT) < 32u)
          __builtin_amdgcn_s_sleep(1);
      }
      __syncthreads();
      __asm__ volatile("" ::: "memory");
    }
  }
}

// ---------------- output projection: out = y @ W_out^T + b_out ----------------
__global__ void __launch_bounds__(256, 1)
proj(const unsigned short* __restrict__ y, const float* __restrict__ Wout,
     const float* __restrict__ bout, float* __restrict__ out)
{
  __shared__ unsigned short ys[128 * 264];
  __shared__ unsigned short wst[128 * 264];

  const int tid  = threadIdx.x;
  const int wave = tid >> 6;
  const int lane = tid & 63;
  const int nl   = lane & 15;
  const int q16  = lane >> 4;
  const int m0   = blockIdx.x * 128;

  f32x4 acc[2][8];
#pragma unroll
  for (int a = 0; a < 2; ++a)
#pragma unroll
    for (int b = 0; b < 8; ++b) acc[a][b] = (f32x4){0.f, 0.f, 0.f, 0.f};

  for (int k0 = 0; k0 < 1024; k0 += 256) {
    {
      int r = tid >> 1, half = tid & 1;
      const uint4* src = (const uint4*)(y + (size_t)(m0 + r) * 1024 + k0 + half * 128);
      uint4* dst = (uint4*)(ys + r * 264 + half * 128);
#pragma unroll
      for (int q = 0; q < 16; ++q) dst[q] = src[q];
    }
    {
      int r = tid >> 1, half = tid & 1;
      const float4* src = (const float4*)(Wout + (size_t)r * 1024 + k0 + half * 128);
      unsigned short* wd = wst + r * 264 + half * 128;
#pragma unroll
      for (int q = 0; q < 32; ++q) *(ushort4*)(wd + q * 4) = cvt4(src[q]);
    }
    __syncthreads();

#pragma unroll
    for (int kk = 0; kk < 8; ++kk) {
      const int ko = kk * 32 + q16 * 8;
      short8 bfr[8];
#pragma unroll
      for (int nt = 0; nt < 8; ++nt)
        bfr[nt] = *(const short8*)(wst + (nt * 16 + nl) * 264 + ko);
#pragma unroll
      for (int mtt = 0; mtt < 2; ++mtt) {
        short8 a = *(const short8*)(ys + ((wave * 2 + mtt) * 16 + nl) * 264 + ko);
#pragma unroll
        for (int nt = 0; nt < 8; ++nt)
          acc[mtt][nt] = __builtin_amdgcn_mfma_f32_16x16x32_bf16(a, bfr[nt], acc[mtt][nt], 0, 0, 0);
      }
    }
    __syncthreads();
  }

#pragma unroll
  for (int mtt = 0; mtt < 2; ++mtt) {
#pragma unroll
    for (int nt = 0; nt < 8; ++nt) {
      int col = nt * 16 + nl;
      float bo = bout[col];
      int rowb = m0 + (wave * 2 + mtt) * 16 + q16 * 4;
#pragma unroll
      for (int r = 0; r < 4; ++r)
        out[(size_t)(rowb + r) * O_SZ + col] = acc[mtt][nt][r] + bo;
    }
  }
}

extern "C" void kernel_launch(void* const* d_in, const int* in_sizes, int n_in,
                              void* d_out, int out_size, void* d_ws, size_t ws_size,
                              hipStream_t stream) {
  const float* x    = (const float*)d_in[0];
  const float* WihF = (const float*)d_in[1];
  const float* WhhF = (const float*)d_in[2];
  const float* bihF = (const float*)d_in[3];
  const float* bhhF = (const float*)d_in[4];
  const float* WihB = (const float*)d_in[5];
  const float* WhhB = (const float*)d_in[6];
  const float* bihB = (const float*)d_in[7];
  const float* bhhB = (const float*)d_in[8];
  const float* Wout = (const float*)d_in[9];
  const float* bout = (const float*)d_in[10];
  float* out = (float*)d_out;
  unsigned char* ws = (unsigned char*)d_ws;

  hipMemsetAsync(ws, 0, (size_t)MEMSET_BYTES, stream);
  cvt_x<<<8192, 256, 0, stream>>>(x, (unsigned short*)(ws + XBF_OFF));
  lstm_scan<<<128, 512, 0, stream>>>((const unsigned short*)(ws + XBF_OFF),
                                     WihF, WhhF, bihF, bhhF,
                                     WihB, WhhB, bihB, bhhB,
                                     ws, out);
  proj<<<512, 256, 0, stream>>>((const unsigned short*)(ws + Y_OFF), Wout, bout, out);
}

// Round 3
// 3375.191 us; speedup vs baseline: 8.1198x; 1.0994x over previous
//
#include <hip/hip_runtime.h>
#include <stdint.h>

#define T_LEN 1024
#define B_SZ  64
#define I_SZ  256
#define H_SZ  512
#define O_SZ  128

// workspace layout (bytes)
#define FLAG_OFF 0ull                 // 4 chains * 32 WGs * 4B = 512 B (monotone step flags)
#define HB_OFF  524288ull             // 2 bufs * 2 dir * 64 * 512 * 2B = 262144
#define Y_OFF   786432ull             // 64*1024*1024*2 = 134217728
#define XBF_OFF 135004160ull          // 64*1024*256*2  = 33554432
#define MEMSET_BYTES 786432ull        // flags + h buffers

typedef __attribute__((ext_vector_type(8))) short short8;
typedef __attribute__((ext_vector_type(4))) float f32x4;

__device__ __forceinline__ unsigned short f2bf(float f) {
  unsigned u = __float_as_uint(f);
  u += 0x7fffu + ((u >> 16) & 1u);
  return (unsigned short)(u >> 16);
}
__device__ __forceinline__ ushort4 cvt4(float4 v) {
  ushort4 p;
  p.x = f2bf(v.x); p.y = f2bf(v.y); p.z = f2bf(v.z); p.w = f2bf(v.w);
  return p;
}
__device__ __forceinline__ float sigm(float x) { return 1.0f / (1.0f + __expf(-x)); }
__device__ __forceinline__ float tanh_f(float x) { return 1.0f - 2.0f / (1.0f + __expf(2.0f * x)); }

// ---------------- input fp32 -> bf16 conversion ----------------
__global__ void __launch_bounds__(256) cvt_x(const float* __restrict__ x,
                                             unsigned short* __restrict__ xb) {
  size_t i = ((size_t)blockIdx.x * 256 + threadIdx.x) * 8;
  float4 a = *(const float4*)(x + i);
  float4 b = *(const float4*)(x + i + 4);
  *(ushort4*)(xb + i)     = cvt4(a);
  *(ushort4*)(xb + i + 4) = cvt4(b);
}

// ---------------- persistent bidirectional LSTM scan ----------------
// grid 128 = 4 chains (dir x batch-group) x 32 unit-group WGs, 512 thr.
// Weights in registers as MFMA B-frags. h via MALL (agent-scope sc1 ops).
// Barrier: distributed per-WG monotone flags, all-wave 32-lane poll.
// x-part MFMA (K=256) precomputed off the critical path into xacc.
__global__ void __launch_bounds__(512, 2)
lstm_scan(const unsigned short* __restrict__ xbf,
          const float* __restrict__ WihF, const float* __restrict__ WhhF,
          const float* __restrict__ bihF, const float* __restrict__ bhhF,
          const float* __restrict__ WihB, const float* __restrict__ WhhB,
          const float* __restrict__ bihB, const float* __restrict__ bhhB,
          unsigned char* __restrict__ ws, float* __restrict__ out)
{
  __shared__ unsigned short xs[2][32][264];  // x double buffer (pitch 264)
  __shared__ unsigned short hs[32][520];     // h staging (pitch 520)
  __shared__ float gbuf[4][32][18];
  __shared__ float cst[32][18];

  const int tid  = threadIdx.x;
  const int lane = tid & 63;
  const int wave = tid >> 6;
  const int nl   = lane & 15;
  const int q16  = lane >> 4;

  const int wg   = blockIdx.x;
  const int d    = wg >> 6;           // 0 fwd, 1 bwd
  const int loc  = wg & 63;
  const int b0   = (loc >> 5) * 32;   // batch-group base
  const int u0   = (loc & 31) * 16;   // unit-group base
  const int grp  = wg >> 5;           // chain id (0..3)
  const int wgid = loc & 31;          // id within chain

  const float* Wih = d ? WihB : WihF;
  const float* Whh = d ? WhhB : WhhF;
  const float* bih = d ? bihB : bihF;
  const float* bhh = d ? bhhB : bhhF;

  const int gate = wave >> 1;   // 0=i 1=f 2=g 3=o
  const int mt   = wave & 1;    // batch half-tile

  // ---- preload B fragments: wfrag[0..7]=Wih(K=256), [8..23]=Whh(K=512) ----
  short8 wfrag[24];
  {
    const int row = gate * H_SZ + u0 + nl;
    const float* wi = Wih + (size_t)row * I_SZ;
    const float* wh = Whh + (size_t)row * H_SZ;
#pragma unroll
    for (int kk = 0; kk < 24; ++kk) {
      const float* src = (kk < 8) ? (wi + kk * 32 + q16 * 8)
                                  : (wh + (kk - 8) * 32 + q16 * 8);
      float4 v0 = ((const float4*)src)[0];
      float4 v1 = ((const float4*)src)[1];
      short8 w;
      w[0] = (short)f2bf(v0.x); w[1] = (short)f2bf(v0.y);
      w[2] = (short)f2bf(v0.z); w[3] = (short)f2bf(v0.w);
      w[4] = (short)f2bf(v1.x); w[5] = (short)f2bf(v1.y);
      w[6] = (short)f2bf(v1.z); w[7] = (short)f2bf(v1.w);
      wfrag[kk] = w;
    }
  }
  const float bias = bih[gate * H_SZ + u0 + nl] + bhh[gate * H_SZ + u0 + nl];

  cst[tid >> 4][tid & 15] = 0.0f;

  unsigned* flags  = (unsigned*)(ws + FLAG_OFF);
  unsigned* hbuf32 = (unsigned*)(ws + HB_OFF);
  unsigned* ybuf32 = (unsigned*)(ws + Y_OFF);
  unsigned* hs32   = (unsigned*)hs;

  const int sm = tid >> 4, sseg = tid & 15;   // x-staging coords

  // ---- prologue: stage x(t0) into xs[0], compute xacc for s=0 ----
  {
    const int t0 = d ? (T_LEN - 1) : 0;
    const uint4* src = (const uint4*)(xbf + ((size_t)(b0 + sm) * T_LEN + t0) * I_SZ + sseg * 16);
    uint4 a = src[0], b = src[1];
    uint4* dst = (uint4*)(&xs[0][sm][sseg * 16]);
    dst[0] = a; dst[1] = b;
  }
  __syncthreads();
  f32x4 xacc = {0.f, 0.f, 0.f, 0.f};
  {
    const unsigned short* xr = &xs[0][mt * 16 + nl][q16 * 8];
#pragma unroll
    for (int kk = 0; kk < 8; ++kk) {
      short8 a = *(const short8*)(xr + kk * 32);
      xacc = __builtin_amdgcn_mfma_f32_16x16x32_bf16(a, wfrag[kk], xacc, 0, 0, 0);
    }
  }
  uint4 px0, px1;
  {
    const int t1 = d ? (T_LEN - 2) : 1;
    const uint4* src = (const uint4*)(xbf + ((size_t)(b0 + sm) * T_LEN + t1) * I_SZ + sseg * 16);
    px0 = src[0]; px1 = src[1];
  }

  for (int s = 0; s < T_LEN; ++s) {
    const int t   = d ? (T_LEN - 1 - s) : s;
    const int cur = s & 1, nxt = cur ^ 1;
    const int rb  = cur ^ 1, wb = cur;

    // ---- wait for all producers of h_{s-1} (distributed flags, all waves) ----
    if (s > 0) {
      const unsigned tgt = (unsigned)s;
      unsigned* fl = flags + grp * 32;
      for (;;) {
        unsigned f = (lane < 32)
          ? __hip_atomic_load(fl + lane, __ATOMIC_RELAXED, __HIP_MEMORY_SCOPE_AGENT)
          : tgt;
        if (__all((int)(f >= tgt))) break;
      }
    }

    // ---- stage h_{s-1} from MALL -> LDS (zeros at s=0 via memset) ----
    {
      unsigned hv[16];
      unsigned* hb = hbuf32 + (size_t)((rb * 2 + d) * B_SZ + b0) * 256;
#pragma unroll
      for (int j = 0; j < 16; ++j)
        hv[j] = __hip_atomic_load(hb + j * 512 + tid, __ATOMIC_RELAXED, __HIP_MEMORY_SCOPE_AGENT);
#pragma unroll
      for (int j = 0; j < 16; ++j) {
        int lin = j * 512 + tid;
        hs32[(lin >> 8) * 260 + (lin & 255)] = hv[j];
      }
    }
    __syncthreads();

    // ---- h-part MFMAs (dual chains), acc seeded with precomputed x-part ----
    f32x4 acc0 = xacc, acc1 = {0.f, 0.f, 0.f, 0.f};
    {
      const unsigned short* ar = &hs[mt * 16 + nl][q16 * 8];
#pragma unroll
      for (int kk = 0; kk < 16; kk += 2) {
        short8 a0 = *(const short8*)(ar + kk * 32);
        short8 a1 = *(const short8*)(ar + (kk + 1) * 32);
        acc0 = __builtin_amdgcn_mfma_f32_16x16x32_bf16(a0, wfrag[8 + kk], acc0, 0, 0, 0);
        acc1 = __builtin_amdgcn_mfma_f32_16x16x32_bf16(a1, wfrag[9 + kk], acc1, 0, 0, 0);
      }
      acc0 += acc1;
    }

    // ---- bias + activation -> gbuf ----
#pragma unroll
    for (int r = 0; r < 4; ++r) {
      float v = acc0[r] + bias;
      v = (gate == 2) ? tanh_f(v) : sigm(v);
      gbuf[gate][mt * 16 + q16 * 4 + r][nl] = v;
    }
    __syncthreads();

    // ---- cell/hidden update + stores ----
    {
      int m = tid >> 4, n = tid & 15;
      float gi = gbuf[0][m][n], gf = gbuf[1][m][n];
      float gg = gbuf[2][m][n], go = gbuf[3][m][n];
      float c = gf * cst[m][n] + gi * gg;
      cst[m][n] = c;
      float h = go * tanh_f(c);
      unsigned hbits = f2bf(h);
      unsigned other = __shfl_xor(hbits, 1);
      if ((tid & 1) == 0) {
        unsigned packed = hbits | (other << 16);
        size_t hi = (size_t)((wb * 2 + d) * B_SZ + b0 + m) * 256 + (u0 + n) / 2;
        __hip_atomic_store(hbuf32 + hi, packed, __ATOMIC_RELAXED, __HIP_MEMORY_SCOPE_AGENT);
        size_t yi = ((size_t)(b0 + m) * T_LEN + t) * 512 + (d * H_SZ + u0 + n) / 2;
        ybuf32[yi] = packed;
      }
      if (s == T_LEN - 1) {
        size_t hi = (size_t)(d * B_SZ + b0 + m) * H_SZ + u0 + n;
        out[8388608ull + hi] = h;            // h_n
        out[8388608ull + 65536ull + hi] = c; // c_n
      }
    }

    // ---- stage next x into xs[nxt] (from prefetch regs) ----
    if (s < T_LEN - 1) {
      uint4* dst = (uint4*)(&xs[nxt][sm][sseg * 16]);
      dst[0] = px0; dst[1] = px1;
    }
    __builtin_amdgcn_s_waitcnt(0);   // drain h (sc1) + y stores
    __syncthreads();                 // whole WG drained; xs[nxt] visible

    if (s < T_LEN - 1) {
      // ---- arrival: parallel flag store (no RMW) ----
      if (tid == 0)
        __hip_atomic_store(flags + grp * 32 + wgid, (unsigned)(s + 1),
                           __ATOMIC_RELAXED, __HIP_MEMORY_SCOPE_AGENT);
      // ---- prefetch x for s+2 ----
      if (s + 2 < T_LEN) {
        const int t2 = d ? (T_LEN - 3 - s) : (s + 2);
        const uint4* src = (const uint4*)(xbf + ((size_t)(b0 + sm) * T_LEN + t2) * I_SZ + sseg * 16);
        px0 = src[0]; px1 = src[1];
      }
      // ---- precompute x-part MFMAs for step s+1 (off critical path) ----
      f32x4 xa = {0.f, 0.f, 0.f, 0.f};
      const unsigned short* xr = &xs[nxt][mt * 16 + nl][q16 * 8];
#pragma unroll
      for (int kk = 0; kk < 8; ++kk) {
        short8 a = *(const short8*)(xr + kk * 32);
        xa = __builtin_amdgcn_mfma_f32_16x16x32_bf16(a, wfrag[kk], xa, 0, 0, 0);
      }
      xacc = xa;
    }
  }
}

// ---------------- output projection: out = y @ W_out^T + b_out ----------------
__global__ void __launch_bounds__(256, 1)
proj(const unsigned short* __restrict__ y, const float* __restrict__ Wout,
     const float* __restrict__ bout, float* __restrict__ out)
{
  __shared__ unsigned short ys[128 * 264];
  __shared__ unsigned short wst[128 * 264];

  const int tid  = threadIdx.x;
  const int wave = tid >> 6;
  const int lane = tid & 63;
  const int nl   = lane & 15;
  const int q16  = lane >> 4;
  const int m0   = blockIdx.x * 128;

  f32x4 acc[2][8];
#pragma unroll
  for (int a = 0; a < 2; ++a)
#pragma unroll
    for (int b = 0; b < 8; ++b) acc[a][b] = (f32x4){0.f, 0.f, 0.f, 0.f};

  for (int k0 = 0; k0 < 1024; k0 += 256) {
    {
      int r = tid >> 1, half = tid & 1;
      const uint4* src = (const uint4*)(y + (size_t)(m0 + r) * 1024 + k0 + half * 128);
      uint4* dst = (uint4*)(ys + r * 264 + half * 128);
#pragma unroll
      for (int q = 0; q < 16; ++q) dst[q] = src[q];
    }
    {
      int r = tid >> 1, half = tid & 1;
      const float4* src = (const float4*)(Wout + (size_t)r * 1024 + k0 + half * 128);
      unsigned short* wd = wst + r * 264 + half * 128;
#pragma unroll
      for (int q = 0; q < 32; ++q) *(ushort4*)(wd + q * 4) = cvt4(src[q]);
    }
    __syncthreads();

#pragma unroll
    for (int kk = 0; kk < 8; ++kk) {
      const int ko = kk * 32 + q16 * 8;
      short8 bfr[8];
#pragma unroll
      for (int nt = 0; nt < 8; ++nt)
        bfr[nt] = *(const short8*)(wst + (nt * 16 + nl) * 264 + ko);
#pragma unroll
      for (int mtt = 0; mtt < 2; ++mtt) {
        short8 a = *(const short8*)(ys + ((wave * 2 + mtt) * 16 + nl) * 264 + ko);
#pragma unroll
        for (int nt = 0; nt < 8; ++nt)
          acc[mtt][nt] = __builtin_amdgcn_mfma_f32_16x16x32_bf16(a, bfr[nt], acc[mtt][nt], 0, 0, 0);
      }
    }
    __syncthreads();
  }

#pragma unroll
  for (int mtt = 0; mtt < 2; ++mtt) {
#pragma unroll
    for (int nt = 0; nt < 8; ++nt) {
      int col = nt * 16 + nl;
      float bo = bout[col];
      int rowb = m0 + (wave * 2 + mtt) * 16 + q16 * 4;
#pragma unroll
      for (int r = 0; r < 4; ++r)
        out[(size_t)(rowb + r) * O_SZ + col] = acc[mtt][nt][r] + bo;
    }
  }
}

extern "C" void kernel_launch(void* const* d_in, const int* in_sizes, int n_in,
                              void* d_out, int out_size, void* d_ws, size_t ws_size,
                              hipStream_t stream) {
  const float* x    = (const float*)d_in[0];
  const float* WihF = (const float*)d_in[1];
  const float* WhhF = (const float*)d_in[2];
  const float* bihF = (const float*)d_in[3];
  const float* bhhF = (const float*)d_in[4];
  const float* WihB = (const float*)d_in[5];
  const float* WhhB = (const float*)d_in[6];
  const float* bihB = (const float*)d_in[7];
  const float* bhhB = (const float*)d_in[8];
  const float* Wout = (const float*)d_in[9];
  const float* bout = (const float*)d_in[10];
  float* out = (float*)d_out;
  unsigned char* ws = (unsigned char*)d_ws;

  hipMemsetAsync(ws, 0, (size_t)MEMSET_BYTES, stream);
  cvt_x<<<8192, 256, 0, stream>>>(x, (unsigned short*)(ws + XBF_OFF));
  lstm_scan<<<128, 512, 0, stream>>>((const unsigned short*)(ws + XBF_OFF),
                                     WihF, WhhF, bihF, bhhF,
                                     WihB, WhhB, bihB, bhhB,
                                     ws, out);
  proj<<<512, 256, 0, stream>>>((const unsigned short*)(ws + Y_OFF), Wout, bout, out);
}